// Round 4
// baseline (144.436 us; speedup 1.0000x reference)
//
#include <hip/hip_runtime.h>

// DynamicSlidingWindowAttention — flash attention, bf16 MFMA, gfx950.
// R4: pre-pass converts K -> bf16 [b,h,t,d] and V -> bf16 transposed
// [b,h,d,t] into d_ws; hot loop stages via 4x dwordx4 + register-prefetch
// pipeline (no cvt, no scalar loads in the K-loop). Body otherwise = R3:
// persistent 512 blocks, atomic work-stealing heavy-first, 2-way KV split,
// S^T = K·Q^T softmax in log2 domain.
// Layouts (m89/m91/m120-verified):
//   mfma_f32_16x16x32_bf16: A[m=lane&15][k=quad*8+j], B[k=quad*8+j][n=lane&15],
//   C/D: col=lane&15, row=quad*4+reg.

constexpr int Bc = 2, Hc = 16, Tc = 2048, Dc = 64;
constexpr int BQ = 64;
constexpr int BK = 64;
constexpr int KSTR = 72;   // LDS row strides (ushort): 2-way banks max (free)
constexpr int VSTR = 72;
constexpr int PSTR = 72;
constexpr int N_ITEMS = Bc * Hc * (Tc / BQ);   // 1024
constexpr float QSCALE = 0.125f * 1.44269504088896340736f;  // 1/sqrt(d) * log2e

// d_ws layout (bytes): [0,4) counter | [256, 256+8MiB) K bf16 | then V^T bf16
constexpr size_t KB_OFF = 256;
constexpr size_t VB_OFF = 256 + (size_t)Bc * Hc * Tc * Dc * 2;
constexpr int HEADE = Tc * Dc;   // elems per head

constexpr int KOFF = 0;
constexpr int VOFF = 9216;
constexpr int POFF = 18432;
constexpr int IBOFF = 27648;

typedef __attribute__((ext_vector_type(8))) short short8;
typedef __attribute__((ext_vector_type(4))) float float4v;

__device__ inline unsigned f2bf_u(float f) {
    union { float f; unsigned u; } v; v.f = f;
    return (v.u + 0x7fffu + ((v.u >> 16) & 1u)) >> 16;   // RNE
}

__device__ inline short8 pack8(const float* t) {
    short8 r;
#pragma unroll
    for (int j = 0; j < 8; j++) r[j] = (short)f2bf_u(t[j]);
    return r;
}

// ---- pre-pass: K convert + V transpose-convert ----
__global__ __launch_bounds__(256)
void preconv_kernel(const float* __restrict__ K, const float* __restrict__ V,
                    unsigned short* __restrict__ Kb, unsigned short* __restrict__ Vtb) {
    const int blk = blockIdx.x;
    const int tid = threadIdx.x;
    if (blk < 2048) {
        // K: straight convert, 8 elems/thread
        const int base = blk * 2048 + tid * 8;
        float4v a = *(const float4v*)(K + base);
        float4v b = *(const float4v*)(K + base + 4);
        float t[8] = {a[0], a[1], a[2], a[3], b[0], b[1], b[2], b[3]};
        *(short8*)(Kb + base) = pack8(t);
    } else {
        // V transpose: block handles one (b*h, 64-row t-chunk)
        __shared__ float tile[64][65];
        const int blk2 = blk - 2048;
        const int bh = blk2 >> 5;
        const int t0 = (blk2 & 31) * 64;
        const float* src = V + (size_t)bh * HEADE + (size_t)t0 * Dc;
#pragma unroll
        for (int i = 0; i < 4; i++) {
            const int r = (tid >> 4) + i * 16;
            const int d4 = (tid & 15) * 4;
            float4v v4 = *(const float4v*)(src + r * Dc + d4);
            tile[r][d4] = v4[0]; tile[r][d4 + 1] = v4[1];
            tile[r][d4 + 2] = v4[2]; tile[r][d4 + 3] = v4[3];
        }
        __syncthreads();
        unsigned short* dst = Vtb + (size_t)bh * HEADE + t0;
#pragma unroll
        for (int i = 0; i < 2; i++) {
            const int d = (tid >> 3) + 32 * i;
            const int c = tid & 7;
            float t[8];
#pragma unroll
            for (int j = 0; j < 8; j++) t[j] = tile[c * 8 + j][d];
            *(short8*)(dst + (size_t)d * Tc + c * 8) = pack8(t);
        }
    }
}

__global__ __launch_bounds__(512, 4)
void dswa_kernel(const float* __restrict__ Q,
                 const unsigned short* __restrict__ Kb,
                 const unsigned short* __restrict__ Vtb,
                 const int* __restrict__ wsz,
                 float* __restrict__ O, unsigned* __restrict__ counter) {
    __shared__ __align__(16) unsigned short LDS[27648 + 8];

    const int tid  = threadIdx.x;
    const int g    = tid >> 8;          // kv-split group 0/1
    const int ltid = tid & 255;
    const int wave = tid >> 6;
    const int wv   = wave & 3;          // q-row group
    const int lane = tid & 63;
    const int quad = lane >> 4;
    const int l16  = lane & 15;

    unsigned short* Kl = &LDS[KOFF + g * 4608];
    unsigned short* Vt = &LDS[VOFF + g * 4608];
    unsigned short* Pl = &LDS[POFF + wave * 1152];
    int* ib = (int*)&LDS[IBOFF];

    // staging assignment (per 256-thread group): 2 chunks each for K and V
    const int srow = ltid >> 3;         // 0..31 (+32 for second chunk)
    const int scol = (ltid & 7) * 8;    // bf16 element offset within 64

    for (;;) {
        if (tid == 0) *ib = (int)atomicAdd(counter, 1u);
        __syncthreads();
        const int idx = *ib;
        if (idx >= N_ITEMS) break;

        // heavy-first: h descending (largest window first), qt descending
        const int b  = idx & 1;
        const int qt = 31 - ((idx >> 1) & 31);
        const int h  = 15 - (idx >> 6);
        const int q0 = qt * BQ;
        const int win = wsz[h];

        const size_t headoff = (size_t)(b * Hc + h) * HEADE;
        const float* Qp = Q + headoff;
        const unsigned short* Kbh = Kb + headoff;
        const unsigned short* Vbh = Vtb + headoff;
        float* Op = O + headoff;

        // ---- Q fragments, pre-scaled (log2 domain) ----
        short8 qf[2];
        {
            const int qrow = q0 + wv * 16 + l16;
#pragma unroll
            for (int c = 0; c < 2; c++) {
                const float* src = Qp + (size_t)qrow * Dc + c * 32 + quad * 8;
                float4v a = *(const float4v*)src;
                float4v d4 = *(const float4v*)(src + 4);
                float t[8] = {a[0]*QSCALE, a[1]*QSCALE, a[2]*QSCALE, a[3]*QSCALE,
                              d4[0]*QSCALE, d4[1]*QSCALE, d4[2]*QSCALE, d4[3]*QSCALE};
                qf[c] = pack8(t);
            }
        }

        float m_i = -1e30f, l_i = 0.0f;
        float4v acc[4];
#pragma unroll
        for (int nb = 0; nb < 4; nb++) acc[nb] = (float4v){0.f, 0.f, 0.f, 0.f};

        const int kv_lo = (max(0, q0 - win)) & ~(BK - 1);
        const int n_tiles = (q0 + BQ - kv_lo) >> 6;
        const int IT = (n_tiles + 1) >> 1;

        const int rg_rel0 = q0 + wv * 16 + l16 - quad * 4;

        // ---- prologue prefetch: tile g into registers ----
        short8 kr0, kr1, vr0, vr1;
        if (g < n_tiles) {
            const int kv0 = kv_lo + g * BK;
            kr0 = *(const short8*)(Kbh + (size_t)(kv0 + srow) * Dc + scol);
            kr1 = *(const short8*)(Kbh + (size_t)(kv0 + srow + 32) * Dc + scol);
            vr0 = *(const short8*)(Vbh + (size_t)srow * Tc + kv0 + scol);
            vr1 = *(const short8*)(Vbh + (size_t)(srow + 32) * Tc + kv0 + scol);
        }

        for (int t = 0; t < IT; ++t) {
            const int ti = g + 2 * t;
            const bool act = ti < n_tiles;
            const int kv0 = kv_lo + ti * BK;

            __syncthreads();   // prev iteration's LDS reads complete

            if (act) {
                *(short8*)&Kl[srow * KSTR + scol] = kr0;
                *(short8*)&Kl[(srow + 32) * KSTR + scol] = kr1;
                *(short8*)&Vt[srow * VSTR + scol] = vr0;
                *(short8*)&Vt[(srow + 32) * VSTR + scol] = vr1;
            }
            __syncthreads();

            // ---- prefetch next tile into registers (overlaps compute) ----
            const int tn = ti + 2;
            if (tn < n_tiles) {
                const int kvn = kv_lo + tn * BK;
                kr0 = *(const short8*)(Kbh + (size_t)(kvn + srow) * Dc + scol);
                kr1 = *(const short8*)(Kbh + (size_t)(kvn + srow + 32) * Dc + scol);
                vr0 = *(const short8*)(Vbh + (size_t)srow * Tc + kvn + scol);
                vr1 = *(const short8*)(Vbh + (size_t)(srow + 32) * Tc + kvn + scol);
            }

            if (act) {
                // ---- S^T = K Q^T (log2 domain) ----
                float4v sT[4];
#pragma unroll
                for (int mb = 0; mb < 4; mb++) {
                    float4v c = {0.f, 0.f, 0.f, 0.f};
#pragma unroll
                    for (int ch = 0; ch < 2; ch++) {
                        short8 kf = *(short8*)&Kl[(mb * 16 + l16) * KSTR + ch * 32 + quad * 8];
                        c = __builtin_amdgcn_mfma_f32_16x16x32_bf16(kf, qf[ch], c, 0, 0, 0);
                    }
                    sT[mb] = c;
                }

                // ---- mask: 0 <= qrow-key <= win as unsigned cmp ----
                const int dbase = rg_rel0 - kv0;
#pragma unroll
                for (int mb = 0; mb < 4; mb++)
#pragma unroll
                    for (int r = 0; r < 4; r++) {
                        const unsigned diff = (unsigned)(dbase - mb * 16 - r);
                        sT[mb][r] = (diff <= (unsigned)win) ? sT[mb][r] : -3.0e38f;
                    }

                // ---- online softmax ----
                float mx = fmaxf(fmaxf(sT[0][0], sT[0][1]), fmaxf(sT[0][2], sT[0][3]));
#pragma unroll
                for (int mb = 1; mb < 4; mb++)
                    mx = fmaxf(mx, fmaxf(fmaxf(sT[mb][0], sT[mb][1]),
                                         fmaxf(sT[mb][2], sT[mb][3])));
                mx = fmaxf(mx, __shfl_xor(mx, 16));
                mx = fmaxf(mx, __shfl_xor(mx, 32));

                const float mn = fmaxf(m_i, mx);
                const float al = exp2f(m_i - mn);
                m_i = mn;

                float rs = 0.f;
                float p[4][4];
#pragma unroll
                for (int mb = 0; mb < 4; mb++)
#pragma unroll
                    for (int r = 0; r < 4; r++) {
                        p[mb][r] = exp2f(sT[mb][r] - mn);
                        rs += p[mb][r];
                    }
                rs += __shfl_xor(rs, 16);
                rs += __shfl_xor(rs, 32);
                l_i = l_i * al + rs;

                // ---- P -> per-wave LDS [qrow=l16][key] ----
#pragma unroll
                for (int mb = 0; mb < 4; mb++) {
                    unsigned u0 = f2bf_u(p[mb][0]) | (f2bf_u(p[mb][1]) << 16);
                    unsigned u1 = f2bf_u(p[mb][2]) | (f2bf_u(p[mb][3]) << 16);
                    unsigned* dst = (unsigned*)&Pl[l16 * PSTR + mb * 16 + quad * 4];
                    dst[0] = u0; dst[1] = u1;
                }

                // ---- rescale acc ----
                float af[4];
#pragma unroll
                for (int r = 0; r < 4; r++) af[r] = __shfl(al, quad * 4 + r);
#pragma unroll
                for (int nb = 0; nb < 4; nb++)
#pragma unroll
                    for (int r = 0; r < 4; r++) acc[nb][r] *= af[r];

                // ---- O += P V ----
                __asm__ volatile("" ::: "memory");
                short8 pf[2];
#pragma unroll
                for (int ch = 0; ch < 2; ch++)
                    pf[ch] = *(short8*)&Pl[l16 * PSTR + ch * 32 + quad * 8];
#pragma unroll
                for (int nb = 0; nb < 4; nb++) {
#pragma unroll
                    for (int ch = 0; ch < 2; ch++) {
                        short8 vf = *(short8*)&Vt[(nb * 16 + l16) * VSTR + ch * 32 + quad * 8];
                        acc[nb] = __builtin_amdgcn_mfma_f32_16x16x32_bf16(pf[ch], vf, acc[nb], 0, 0, 0);
                    }
                }
            }
        }

        // ---- merge KV-split partials, store ----
        __syncthreads();
        float* fl = (float*)LDS;
        if (g == 1) {
            if (quad == 0) {
                fl[wv * 16 + l16] = m_i;
                fl[64 + wv * 16 + l16] = l_i;
            }
#pragma unroll
            for (int r = 0; r < 4; r++) {
                const int row = wv * 16 + quad * 4 + r;
#pragma unroll
                for (int nb = 0; nb < 4; nb++)
                    fl[128 + row * 65 + nb * 16 + l16] = acc[nb][r];
            }
        }
        __syncthreads();
        if (g == 0) {
            const float m1 = fl[wv * 16 + l16];
            const float l1 = fl[64 + wv * 16 + l16];
            const float M  = fmaxf(m_i, m1);
            const float a0 = exp2f(m_i - M);
            const float a1 = exp2f(m1 - M);
            const float lt = l_i * a0 + l1 * a1;
            const float inv = 1.0f / lt;
            float c0[4], c1[4], iv[4];
#pragma unroll
            for (int r = 0; r < 4; r++) {
                c0[r] = __shfl(a0, quad * 4 + r);
                c1[r] = __shfl(a1, quad * 4 + r);
                iv[r] = __shfl(inv, quad * 4 + r);
            }
#pragma unroll
            for (int r = 0; r < 4; r++) {
                const int row = wv * 16 + quad * 4 + r;
                float* dst = Op + (size_t)(q0 + row) * Dc;
#pragma unroll
                for (int nb = 0; nb < 4; nb++) {
                    const float o1 = fl[128 + row * 65 + nb * 16 + l16];
                    dst[nb * 16 + l16] = (acc[nb][r] * c0[r] + o1 * c1[r]) * iv[r];
                }
            }
        }
    }
}

extern "C" void kernel_launch(void* const* d_in, const int* in_sizes, int n_in,
                              void* d_out, int out_size, void* d_ws, size_t ws_size,
                              hipStream_t stream) {
    (void)in_sizes; (void)n_in; (void)ws_size; (void)out_size;
    const float* Q = (const float*)d_in[0];
    const float* K = (const float*)d_in[1];
    const float* V = (const float*)d_in[2];
    const int* wsz = (const int*)d_in[3];
    float* Out = (float*)d_out;

    unsigned* counter = (unsigned*)d_ws;
    unsigned short* Kb  = (unsigned short*)((char*)d_ws + KB_OFF);
    unsigned short* Vtb = (unsigned short*)((char*)d_ws + VB_OFF);

    hipMemsetAsync(counter, 0, sizeof(unsigned), stream);
    preconv_kernel<<<dim3(3072), dim3(256), 0, stream>>>(K, V, Kb, Vtb);
    dswa_kernel<<<dim3(512), dim3(512), 0, stream>>>(Q, Kb, Vtb, wsz, Out, counter);
}

// Round 5
// 130.636 us; speedup vs baseline: 1.1056x; 1.1056x over previous
//
#include <hip/hip_runtime.h>
#include <hip/hip_bf16.h>

// DynamicSlidingWindowAttention — flash attention, bf16 MFMA, gfx950.
// R5: static-max softmax (C=16 folded into MFMA acc init; no per-iter max
// tree / shuffles / alpha rescale / m,l chain), l via MFMA against a ones
// row appended to V^T, interior-tile fast path (mask skipped), packed bf16
// cvt for P. Skeleton = R4: prepass K->bf16 / V->bf16^T in d_ws, persistent
// 512 blocks, work-stealing heavy-first, 2-way KV split, register-prefetch.
// Layouts (m89/m91/m120-verified):
//   mfma_f32_16x16x32_bf16: A[m=lane&15][k=quad*8+j], B[k=quad*8+j][n=lane&15],
//   C/D: col=lane&15, row=quad*4+reg.

constexpr int Bc = 2, Hc = 16, Tc = 2048, Dc = 64;
constexpr int BQ = 64;
constexpr int BK = 64;
constexpr int KSTR = 72;   // LDS row strides (ushort): <=2-way banks (free)
constexpr int VSTR = 72;
constexpr int PSTR = 72;
constexpr int N_ITEMS = Bc * Hc * (Tc / BQ);   // 1024
constexpr float QSCALE = 0.125f * 1.44269504088896340736f;  // 1/sqrt(d)*log2e
constexpr float CMAX = 16.0f;   // static softmax max (log2 domain)

// d_ws layout (bytes): [0,4) counter | [256,+8MiB) K bf16 | then V^T bf16
constexpr size_t KB_OFF = 256;
constexpr size_t VB_OFF = 256 + (size_t)Bc * Hc * Tc * Dc * 2;
constexpr int HEADE = Tc * Dc;

// LDS map (ushort units): K 2x64x72 | V^T 2x80x72 (rows 64..79: ones row 64,
// zeros 65..79, for the l=P*1 MFMA) | P 8x16x72 | item broadcast
constexpr int KOFF = 0;               // 9216
constexpr int VOFF = 9216;            // 2 * 5760 = 11520
constexpr int POFF = 20736;           // 8 * 1152 = 9216
constexpr int IBOFF = 29952;

typedef __attribute__((ext_vector_type(8))) short short8;
typedef __attribute__((ext_vector_type(4))) float float4v;

__device__ inline unsigned f2bf_u(float f) {
    union { float f; unsigned u; } v; v.f = f;
    return (v.u + 0x7fffu + ((v.u >> 16) & 1u)) >> 16;   // RNE
}

__device__ inline short8 pack8(const float* t) {
    short8 r;
#pragma unroll
    for (int j = 0; j < 8; j++) r[j] = (short)f2bf_u(t[j]);
    return r;
}

__device__ inline unsigned pk_bf16(float a, float b) {
    __hip_bfloat162 h = __float22bfloat162_rn(make_float2(a, b));
    union { __hip_bfloat162 h; unsigned u; } v; v.h = h;
    return v.u;
}

// ---- pre-pass: K convert + V transpose-convert ----
__global__ __launch_bounds__(256)
void preconv_kernel(const float* __restrict__ K, const float* __restrict__ V,
                    unsigned short* __restrict__ Kb, unsigned short* __restrict__ Vtb) {
    const int blk = blockIdx.x;
    const int tid = threadIdx.x;
    if (blk < 2048) {
        const int base = blk * 2048 + tid * 8;
        float4v a = *(const float4v*)(K + base);
        float4v b = *(const float4v*)(K + base + 4);
        float t[8] = {a[0], a[1], a[2], a[3], b[0], b[1], b[2], b[3]};
        *(short8*)(Kb + base) = pack8(t);
    } else {
        __shared__ float tile[64][65];
        const int blk2 = blk - 2048;
        const int bh = blk2 >> 5;
        const int t0 = (blk2 & 31) * 64;
        const float* src = V + (size_t)bh * HEADE + (size_t)t0 * Dc;
#pragma unroll
        for (int i = 0; i < 4; i++) {
            const int r = (tid >> 4) + i * 16;
            const int d4 = (tid & 15) * 4;
            float4v v4 = *(const float4v*)(src + r * Dc + d4);
            tile[r][d4] = v4[0]; tile[r][d4 + 1] = v4[1];
            tile[r][d4 + 2] = v4[2]; tile[r][d4 + 3] = v4[3];
        }
        __syncthreads();
        unsigned short* dst = Vtb + (size_t)bh * HEADE + t0;
#pragma unroll
        for (int i = 0; i < 2; i++) {
            const int d = (tid >> 3) + 32 * i;
            const int c = tid & 7;
            float t[8];
#pragma unroll
            for (int j = 0; j < 8; j++) t[j] = tile[c * 8 + j][d];
            *(short8*)(dst + (size_t)d * Tc + c * 8) = pack8(t);
        }
    }
}

__global__ __launch_bounds__(512, 4)
void dswa_kernel(const float* __restrict__ Q,
                 const unsigned short* __restrict__ Kb,
                 const unsigned short* __restrict__ Vtb,
                 const int* __restrict__ wsz,
                 float* __restrict__ O, unsigned* __restrict__ counter) {
    __shared__ __align__(16) unsigned short LDS[29960];

    const int tid  = threadIdx.x;
    const int g    = tid >> 8;          // kv-split group 0/1
    const int ltid = tid & 255;
    const int wave = tid >> 6;
    const int wv   = wave & 3;          // q-row group
    const int lane = tid & 63;
    const int quad = lane >> 4;
    const int l16  = lane & 15;

    unsigned short* Kl = &LDS[KOFF + g * 4608];
    unsigned short* Vt = &LDS[VOFF + g * 5760];
    unsigned short* Pl = &LDS[POFF + wave * 1152];
    int* ib = (int*)&LDS[IBOFF];

    // init V^T rows 64..79 once: row 64 = 1.0 (bf16 0x3F80), rows 65..79 = 0
    for (int i = ltid; i < 16 * VSTR; i += 256) {
        const int row = i / VSTR, col = i % VSTR;
        Vt[(64 + row) * VSTR + col] = (row == 0 && col < 64) ? 0x3F80 : 0;
    }

    const int srow = ltid >> 3;         // staging row 0..31 (+32)
    const int scol = (ltid & 7) * 8;

    for (;;) {
        if (tid == 0) *ib = (int)atomicAdd(counter, 1u);
        __syncthreads();
        const int idx = *ib;
        if (idx >= N_ITEMS) break;

        // heavy-first: h descending (largest window first), qt descending
        const int b  = idx & 1;
        const int qt = 31 - ((idx >> 1) & 31);
        const int h  = 15 - (idx >> 6);
        const int q0 = qt * BQ;
        const int win = wsz[h];

        const size_t headoff = (size_t)(b * Hc + h) * HEADE;
        const float* Qp = Q + headoff;
        const unsigned short* Kbh = Kb + headoff;
        const unsigned short* Vbh = Vtb + headoff;
        float* Op = O + headoff;

        // ---- Q fragments, pre-scaled (log2 domain) ----
        short8 qf[2];
        {
            const int qrow = q0 + wv * 16 + l16;
#pragma unroll
            for (int c = 0; c < 2; c++) {
                const float* src = Qp + (size_t)qrow * Dc + c * 32 + quad * 8;
                float4v a = *(const float4v*)src;
                float4v d4 = *(const float4v*)(src + 4);
                float t[8] = {a[0]*QSCALE, a[1]*QSCALE, a[2]*QSCALE, a[3]*QSCALE,
                              d4[0]*QSCALE, d4[1]*QSCALE, d4[2]*QSCALE, d4[3]*QSCALE};
                qf[c] = pack8(t);
            }
        }

        float4v acc[4];   // O accumulator (unnormalized)
        float4v acc5;     // l accumulator via P*ones (col l16==0 valid)
#pragma unroll
        for (int nb = 0; nb < 4; nb++) acc[nb] = (float4v){0.f, 0.f, 0.f, 0.f};
        acc5 = (float4v){0.f, 0.f, 0.f, 0.f};

        const int kv_lo = (max(0, q0 - win)) & ~(BK - 1);
        const int n_tiles = (q0 + BQ - kv_lo) >> 6;
        const int IT = (n_tiles + 1) >> 1;

        const int rw0 = q0 + wv * 16;          // wave's first q row
        const int rg_rel0 = rw0 + l16 - quad * 4;

        // ---- prologue prefetch: tile g into registers ----
        short8 kr0, kr1, vr0, vr1;
        if (g < n_tiles) {
            const int kv0 = kv_lo + g * BK;
            kr0 = *(const short8*)(Kbh + (size_t)(kv0 + srow) * Dc + scol);
            kr1 = *(const short8*)(Kbh + (size_t)(kv0 + srow + 32) * Dc + scol);
            vr0 = *(const short8*)(Vbh + (size_t)srow * Tc + kv0 + scol);
            vr1 = *(const short8*)(Vbh + (size_t)(srow + 32) * Tc + kv0 + scol);
        }

        for (int t = 0; t < IT; ++t) {
            const int ti = g + 2 * t;
            const bool act = ti < n_tiles;
            const int kv0 = kv_lo + ti * BK;

            __syncthreads();   // prev iteration's LDS reads complete

            if (act) {
                *(short8*)&Kl[srow * KSTR + scol] = kr0;
                *(short8*)&Kl[(srow + 32) * KSTR + scol] = kr1;
                *(short8*)&Vt[srow * VSTR + scol] = vr0;
                *(short8*)&Vt[(srow + 32) * VSTR + scol] = vr1;
            }
            __syncthreads();

            // prefetch next tile (overlaps compute)
            const int tn = ti + 2;
            if (tn < n_tiles) {
                const int kvn = kv_lo + tn * BK;
                kr0 = *(const short8*)(Kbh + (size_t)(kvn + srow) * Dc + scol);
                kr1 = *(const short8*)(Kbh + (size_t)(kvn + srow + 32) * Dc + scol);
                vr0 = *(const short8*)(Vbh + (size_t)srow * Tc + kvn + scol);
                vr1 = *(const short8*)(Vbh + (size_t)(srow + 32) * Tc + kvn + scol);
            }

            if (act) {
                // ---- S^T = K Q^T - CMAX (log2 domain; -CMAX via acc init) ----
                float4v sT[4];
#pragma unroll
                for (int mb = 0; mb < 4; mb++) {
                    float4v c = {-CMAX, -CMAX, -CMAX, -CMAX};
#pragma unroll
                    for (int ch = 0; ch < 2; ch++) {
                        short8 kf = *(short8*)&Kl[(mb * 16 + l16) * KSTR + ch * 32 + quad * 8];
                        c = __builtin_amdgcn_mfma_f32_16x16x32_bf16(kf, qf[ch], c, 0, 0, 0);
                    }
                    sT[mb] = c;
                }

                // ---- mask only on boundary tiles (wave-uniform test) ----
                const bool interior = (rw0 >= kv0 + 63) && (rw0 + 15 - kv0 <= win);
                if (!interior) {
                    const int dbase = rg_rel0 - kv0;
#pragma unroll
                    for (int mb = 0; mb < 4; mb++)
#pragma unroll
                        for (int r = 0; r < 4; r++) {
                            const unsigned diff = (unsigned)(dbase - mb * 16 - r);
                            sT[mb][r] = (diff <= (unsigned)win) ? sT[mb][r] : -3.0e38f;
                        }
                }

                // ---- p = exp2(s' - C); no max tree, no shuffles, no alpha ----
                float p[4][4];
#pragma unroll
                for (int mb = 0; mb < 4; mb++)
#pragma unroll
                    for (int r = 0; r < 4; r++)
                        p[mb][r] = exp2f(sT[mb][r]);

                // ---- P -> per-wave LDS [qrow=l16][key], packed cvt ----
#pragma unroll
                for (int mb = 0; mb < 4; mb++) {
                    unsigned* dst = (unsigned*)&Pl[l16 * PSTR + mb * 16 + quad * 4];
                    dst[0] = pk_bf16(p[mb][0], p[mb][1]);
                    dst[1] = pk_bf16(p[mb][2], p[mb][3]);
                }

                // ---- O += P V ; l += P * ones (extra nb=4 block) ----
                __asm__ volatile("" ::: "memory");
                short8 pf[2];
#pragma unroll
                for (int ch = 0; ch < 2; ch++)
                    pf[ch] = *(short8*)&Pl[l16 * PSTR + ch * 32 + quad * 8];
#pragma unroll
                for (int nb = 0; nb < 4; nb++) {
#pragma unroll
                    for (int ch = 0; ch < 2; ch++) {
                        short8 vf = *(short8*)&Vt[(nb * 16 + l16) * VSTR + ch * 32 + quad * 8];
                        acc[nb] = __builtin_amdgcn_mfma_f32_16x16x32_bf16(pf[ch], vf, acc[nb], 0, 0, 0);
                    }
                }
#pragma unroll
                for (int ch = 0; ch < 2; ch++) {
                    short8 vf = *(short8*)&Vt[(64 + l16) * VSTR + ch * 32 + quad * 8];
                    acc5 = __builtin_amdgcn_mfma_f32_16x16x32_bf16(pf[ch], vf, acc5, 0, 0, 0);
                }
            }
        }

        // ---- merge the two KV-split partials (pure adds), store ----
        __syncthreads();
        float* fl = (float*)LDS;   // 64 rows x stride 66: cols 0..63 = O, 64 = l
        if (g == 1) {
#pragma unroll
            for (int r = 0; r < 4; r++) {
                const int row = wv * 16 + quad * 4 + r;
#pragma unroll
                for (int nb = 0; nb < 4; nb++)
                    fl[row * 66 + nb * 16 + l16] = acc[nb][r];
                if (l16 == 0) fl[row * 66 + 64] = acc5[r];
            }
        }
        __syncthreads();
        if (g == 0) {
#pragma unroll
            for (int r = 0; r < 4; r++) {
                const int row = wv * 16 + quad * 4 + r;
                const float l0 = __shfl(acc5[r], quad * 16);   // col 0 of this row
                const float lt = l0 + fl[row * 66 + 64];
                const float inv = 1.0f / lt;
                float* dst = Op + (size_t)(q0 + row) * Dc;
#pragma unroll
                for (int nb = 0; nb < 4; nb++)
                    dst[nb * 16 + l16] = (acc[nb][r] + fl[row * 66 + nb * 16 + l16]) * inv;
            }
        }
    }
}

extern "C" void kernel_launch(void* const* d_in, const int* in_sizes, int n_in,
                              void* d_out, int out_size, void* d_ws, size_t ws_size,
                              hipStream_t stream) {
    (void)in_sizes; (void)n_in; (void)ws_size; (void)out_size;
    const float* Q = (const float*)d_in[0];
    const float* K = (const float*)d_in[1];
    const float* V = (const float*)d_in[2];
    const int* wsz = (const int*)d_in[3];
    float* Out = (float*)d_out;

    unsigned* counter = (unsigned*)d_ws;
    unsigned short* Kb  = (unsigned short*)((char*)d_ws + KB_OFF);
    unsigned short* Vtb = (unsigned short*)((char*)d_ws + VB_OFF);

    hipMemsetAsync(counter, 0, sizeof(unsigned), stream);
    preconv_kernel<<<dim3(3072), dim3(256), 0, stream>>>(K, V, Kb, Vtb);
    dswa_kernel<<<dim3(512), dim3(512), 0, stream>>>(Q, Kb, Vtb, wsz, Out, counter);
}